// Round 4
// baseline (425.666 us; speedup 1.0000x reference)
//
#include <hip/hip_runtime.h>
#include <hip/hip_bf16.h>
#include <cstdint>
#include <cstddef>

#define DIME 2048
#define NH 32
#define NKV 8
#define HD 64
#define BB 2
#define SSEQ 2048
#define PACKED (DIME + 2*NKV*HD)   // 3072
#define MTOT (BB*SSEQ)             // 4096

typedef __attribute__((ext_vector_type(8))) short bf16x8;
typedef __attribute__((ext_vector_type(4))) float f32x4;

struct FalseT { static constexpr bool value = false; };
struct TrueT  { static constexpr bool value = true;  };

__device__ __forceinline__ short f2b(float f) {
  unsigned u = __builtin_bit_cast(unsigned, f);
  u += 0x7fffu + ((u >> 16) & 1u);
  return (short)(u >> 16);
}
__device__ __forceinline__ float b2f(short s) {
  unsigned u = ((unsigned)(unsigned short)s) << 16;
  return __builtin_bit_cast(float, u);
}

__device__ __forceinline__ void gload_lds16(const void* g, void* l) {
  __builtin_amdgcn_global_load_lds(
      (const __attribute__((address_space(1))) void*)g,
      (__attribute__((address_space(3))) void*)l, 16, 0, 0);
}

// ---------------- cast fp32 -> bf16 (vectorized) ----------------
__global__ __launch_bounds__(256) void cast_bf16(const float* __restrict__ in,
                                                 short* __restrict__ out, int n4) {
  int i = blockIdx.x * blockDim.x + threadIdx.x;
  int stride = gridDim.x * blockDim.x;
  for (; i < n4; i += stride) {
    float4 v = ((const float4*)in)[i];
    short4 o;
    o.x = f2b(v.x); o.y = f2b(v.y); o.z = f2b(v.z); o.w = f2b(v.w);
    ((short4*)out)[i] = o;
  }
}

// ---------------- transpose + cast: in fp32 [R][C] -> out bf16 [C][R] ----------------
__global__ __launch_bounds__(256) void transpose_cast(const float* __restrict__ in,
                                                      short* __restrict__ out,
                                                      int R, int C) {
  __shared__ float tile[32][33];
  int bx = blockIdx.x * 32;
  int by = blockIdx.y * 32;
  int tx = threadIdx.x;
  int ty = threadIdx.y;
  #pragma unroll
  for (int j = 0; j < 4; ++j)
    tile[ty + j*8][tx] = in[(size_t)(by + ty + j*8) * C + bx + tx];
  __syncthreads();
  #pragma unroll
  for (int j = 0; j < 4; ++j)
    out[(size_t)(bx + ty + j*8) * R + by + tx] = f2b(tile[tx][ty + j*8]);
}

// ---------------- RoPE cos/sin table: [S][32] ----------------
__global__ __launch_bounds__(256) void rope_table(float* __restrict__ ctab,
                                                  float* __restrict__ stab) {
  int t = blockIdx.x * blockDim.x + threadIdx.x;
  int s = t >> 5, i = t & 31;
  float theta = 1.0f / powf(10000.0f, (float)(2 * i) * (1.0f / (float)HD));
  float ang = (float)s * theta;
  float sn, cs;
  sincosf(ang, &sn, &cs);
  ctab[t] = cs;
  stab[t] = sn;
}

// ---------------- GEMM: A[M][K] bf16, BT[N][K] bf16 -> C[M][N] ----------------
template<bool BF16_OUT>
__global__ __launch_bounds__(256) void gemm_bt(const short* __restrict__ A,
                                               const short* __restrict__ BT,
                                               void* __restrict__ Cout,
                                               int M, int N, int K) {
  __shared__ __align__(16) short As[128 * 32];
  __shared__ __align__(16) short Bs[128 * 32];
  const int tid = threadIdx.x;
  const int l = tid & 63, w = tid >> 6;
  const int lr = l & 15, lg = l >> 4;
  const int wm = w >> 1, wn = w & 1;
  const int bm = blockIdx.x * 128, bn = blockIdx.y * 128;

  f32x4 acc[4][4];
  #pragma unroll
  for (int m = 0; m < 4; ++m)
    #pragma unroll
    for (int n = 0; n < 4; ++n) {
      f32x4 z = {0.f, 0.f, 0.f, 0.f};
      acc[m][n] = z;
    }

  for (int k0 = 0; k0 < K; k0 += 32) {
    #pragma unroll
    for (int c = 0; c < 2; ++c) {
      const int cb = c * 256 + w * 64;
      const int chunk = cb + l;
      const int row = chunk >> 2, col = (chunk & 3) * 8;
      gload_lds16(A  + (size_t)(bm + row) * K + k0 + col, As + cb * 8);
      gload_lds16(BT + (size_t)(bn + row) * K + k0 + col, Bs + cb * 8);
    }
    __syncthreads();
    bf16x8 af[4], bf[4];
    #pragma unroll
    for (int m = 0; m < 4; ++m)
      af[m] = *(const bf16x8*)&As[(wm * 64 + m * 16 + lr) * 32 + lg * 8];
    #pragma unroll
    for (int n = 0; n < 4; ++n)
      bf[n] = *(const bf16x8*)&Bs[(wn * 64 + n * 16 + lr) * 32 + lg * 8];
    #pragma unroll
    for (int m = 0; m < 4; ++m)
      #pragma unroll
      for (int n = 0; n < 4; ++n)
        acc[m][n] = __builtin_amdgcn_mfma_f32_16x16x32_bf16(af[m], bf[n], acc[m][n], 0, 0, 0);
    __syncthreads();
  }

  #pragma unroll
  for (int m = 0; m < 4; ++m)
    #pragma unroll
    for (int n = 0; n < 4; ++n)
      #pragma unroll
      for (int r = 0; r < 4; ++r) {
        int row = bm + wm * 64 + m * 16 + lg * 4 + r;
        int col = bn + wn * 64 + n * 16 + lr;
        if (BF16_OUT)
          ((short*)Cout)[(size_t)row * N + col] = f2b(acc[m][n][r]);
        else
          ((float*)Cout)[(size_t)row * N + col] = acc[m][n][r];
      }
}

// ---------------- RoPE + split qkv -> Q [b][h][s][64] (PRESCALED), K [b][kvh][s][64] ----------------
__global__ __launch_bounds__(256) void rope_split(const short* __restrict__ qkv,
                                                  const float* __restrict__ ctab,
                                                  const float* __restrict__ stab,
                                                  short* __restrict__ Qo,
                                                  short* __restrict__ Ko) {
  int w = threadIdx.x >> 6, l = threadIdx.x & 63;
  int job = blockIdx.x * 4 + w;
  int b = job / (SSEQ * 40);
  int rem = job % (SSEQ * 40);
  int s = rem / 40;
  int hh = rem % 40;
  size_t base = (size_t)(b * SSEQ + s) * PACKED;
  int off = (hh < 32) ? (hh * HD + l) : (DIME + (hh - 32) * HD + l);
  float x = b2f(qkv[base + off]);
  float other = __shfl_xor(x, 1);
  int i = l >> 1;
  float cs = ctab[s * 32 + i], sn = stab[s * 32 + i];
  float o = (l & 1) ? (x * cs + other * sn) : (x * cs - other * sn);
  if (hh < 32) {
    o *= 0.180336880f;  // 0.125 * log2(e)
    Qo[((size_t)(b * NH + hh) * SSEQ + s) * HD + l] = f2b(o);
  } else {
    Ko[((size_t)(b * NKV + (hh - 32)) * SSEQ + s) * HD + l] = f2b(o);
  }
}

// ---------------- V transpose: qkv v-slice [s][64] -> VT [b][kvh][64][S] ----------------
__global__ __launch_bounds__(256) void v_transpose(const short* __restrict__ qkv,
                                                   short* __restrict__ VT) {
  __shared__ __align__(16) short tile[64][72];
  int bkv = blockIdx.x >> 5;
  int st = blockIdx.x & 31;
  int s0 = st * 64;
  int t = threadIdx.x;
  int srow = t >> 2, dq = (t & 3) * 16;
  size_t rowbase = (size_t)((bkv >> 3) * SSEQ + s0 + srow) * PACKED
                   + (DIME + NKV * HD) + (bkv & 7) * HD + dq;
  bf16x8 v0 = *(const bf16x8*)&qkv[rowbase];
  bf16x8 v1 = *(const bf16x8*)&qkv[rowbase + 8];
  #pragma unroll
  for (int j = 0; j < 8; ++j) tile[dq + j][srow] = v0[j];
  #pragma unroll
  for (int j = 0; j < 8; ++j) tile[dq + 8 + j][srow] = v1[j];
  __syncthreads();
  int d = t >> 2, sq = (t & 3) * 16;
  size_t obase = ((size_t)bkv * HD + d) * SSEQ + s0 + sq;
  *(bf16x8*)&VT[obase]     = *(const bf16x8*)&tile[d][sq];
  *(bf16x8*)&VT[obase + 8] = *(const bf16x8*)&tile[d][sq + 8];
}

// ---------------- Flash attention: causal GQA, v4 ----------------
// One chunk (32 q-rows) per wave; 4096 jobs over 1024 blocks (4 blocks/CU).
// Heavy-first block order: c = 63 - (blockIdx>>4); all 4 waves in a block
// share c (uniform duration). VGPR capped via __launch_bounds__(256,4):
// mask/exp2 in-place in sacc, V fragments loaded after softmax.
__global__ __launch_bounds__(256, 4) void attn_fwd(const short* __restrict__ Q,
                                                   const short* __restrict__ K,
                                                   const short* __restrict__ VT,
                                                   short* __restrict__ Aout) {
  __shared__ __align__(16) short Plds[4][32 * 64];
  const int tid = threadIdx.x, l = tid & 63, w = tid >> 6;
  const int lr = l & 15, lg = l >> 4;
  const int c = 63 - (blockIdx.x >> 4);    // chunk index, heavy first
  const int bh = (blockIdx.x & 15) * 4 + w;
  const int b = bh >> 5, h = bh & 31, kvh = h >> 2;
  const short* Qp = Q + (size_t)(b * NH + h) * SSEQ * HD;
  const short* Kp = K + (size_t)(b * NKV + kvh) * SSEQ * HD;
  const short* Vp = VT + (size_t)(b * NKV + kvh) * HD * SSEQ;
  short* Pw = (short*)Plds[w];
  const int q0 = c * 32;

  bf16x8 qf[2][2];
  #pragma unroll
  for (int m = 0; m < 2; ++m)
    #pragma unroll
    for (int kh = 0; kh < 2; ++kh)
      qf[m][kh] = *(const bf16x8*)&Qp[(size_t)(q0 + m * 16 + lr) * HD + kh * 32 + lg * 8];

  f32x4 O[2][4];
  #pragma unroll
  for (int m = 0; m < 2; ++m)
    #pragma unroll
    for (int d = 0; d < 4; ++d) { f32x4 z = {0.f,0.f,0.f,0.f}; O[m][d] = z; }
  float mrun[2][4], lpart[2][4];
  #pragma unroll
  for (int m = 0; m < 2; ++m)
    #pragma unroll
    for (int r = 0; r < 4; ++r) { mrun[m][r] = -3e38f; lpart[m][r] = 0.f; }

  auto step = [&](int kv0, auto diag_tag) {
    constexpr bool DIAG = decltype(diag_tag)::value;
    bf16x8 kf[4][2];
    #pragma unroll
    for (int n = 0; n < 4; ++n)
      #pragma unroll
      for (int kh = 0; kh < 2; ++kh)
        kf[n][kh] = *(const bf16x8*)&Kp[(size_t)(kv0 + n * 16 + lr) * HD + kh * 32 + lg * 8];
    // --- QK^T (scores already in exp2-domain via prescaled Q) ---
    f32x4 sacc[2][4];
    #pragma unroll
    for (int m = 0; m < 2; ++m)
      #pragma unroll
      for (int n = 0; n < 4; ++n) { f32x4 z = {0.f,0.f,0.f,0.f}; sacc[m][n] = z; }
    #pragma unroll
    for (int m = 0; m < 2; ++m)
      #pragma unroll
      for (int n = 0; n < 4; ++n) {
        sacc[m][n] = __builtin_amdgcn_mfma_f32_16x16x32_bf16(qf[m][0], kf[n][0], sacc[m][n], 0, 0, 0);
        sacc[m][n] = __builtin_amdgcn_mfma_f32_16x16x32_bf16(qf[m][1], kf[n][1], sacc[m][n], 0, 0, 0);
      }
    // --- mask (diag only, in place) + per-lane max ---
    float pmax[2][4];
    #pragma unroll
    for (int m = 0; m < 2; ++m)
      #pragma unroll
      for (int r = 0; r < 4; ++r) pmax[m][r] = -3e38f;
    #pragma unroll
    for (int m = 0; m < 2; ++m)
      #pragma unroll
      for (int n = 0; n < 4; ++n)
        #pragma unroll
        for (int r = 0; r < 4; ++r) {
          if (DIAG) {
            if ((kv0 + n * 16 + lr) > (q0 + m * 16 + lg * 4 + r)) sacc[m][n][r] = -3e38f;
          }
          pmax[m][r] = fmaxf(pmax[m][r], sacc[m][n][r]);
        }
    // --- defer-max: rescale only when per-lane max grew past threshold ---
    int ok = 1;
    #pragma unroll
    for (int m = 0; m < 2; ++m)
      #pragma unroll
      for (int r = 0; r < 4; ++r)
        ok &= (pmax[m][r] <= mrun[m][r] + 11.0f);
    if (!__all(ok)) {
      #pragma unroll
      for (int off = 1; off < 16; off <<= 1)
        #pragma unroll
        for (int m = 0; m < 2; ++m)
          #pragma unroll
          for (int r = 0; r < 4; ++r)
            pmax[m][r] = fmaxf(pmax[m][r], __shfl_xor(pmax[m][r], off));
      #pragma unroll
      for (int m = 0; m < 2; ++m)
        #pragma unroll
        for (int r = 0; r < 4; ++r) {
          float mn = fmaxf(mrun[m][r], pmax[m][r]);
          float corr = exp2f(mrun[m][r] - mn);
          mrun[m][r] = mn;
          lpart[m][r] *= corr;
          #pragma unroll
          for (int d = 0; d < 4; ++d) O[m][d][r] *= corr;
        }
    }
    // --- exp2 (in place) + P store (swizzled) + l partials ---
    #pragma unroll
    for (int m = 0; m < 2; ++m)
      #pragma unroll
      for (int r = 0; r < 4; ++r) {
        float ls = 0.f;
        #pragma unroll
        for (int n = 0; n < 4; ++n) {
          float e = exp2f(sacc[m][n][r] - mrun[m][r]);
          ls += e;
          int row = m * 16 + lg * 4 + r;
          int byte = (row * 64 + n * 16 + lr) * 2;
          byte ^= (row & 7) << 4;
          unsigned u = __builtin_bit_cast(unsigned, e);
          Pw[byte >> 1] = (short)((u + 0x8000u) >> 16);
        }
        lpart[m][r] += ls;
      }
    // --- PV (V fragments loaded here, not earlier: keeps VGPR under 128) ---
    bf16x8 pf[2][2];
    #pragma unroll
    for (int m = 0; m < 2; ++m)
      #pragma unroll
      for (int kh = 0; kh < 2; ++kh) {
        int byte = ((m * 16 + lr) * 64 + kh * 32 + lg * 8) * 2;
        byte ^= (lr & 7) << 4;
        pf[m][kh] = *(const bf16x8*)&Pw[byte >> 1];
      }
    bf16x8 vf[4][2];
    #pragma unroll
    for (int d = 0; d < 4; ++d)
      #pragma unroll
      for (int kh = 0; kh < 2; ++kh)
        vf[d][kh] = *(const bf16x8*)&Vp[(size_t)(d * 16 + lr) * SSEQ + kv0 + kh * 32 + lg * 8];
    #pragma unroll
    for (int m = 0; m < 2; ++m)
      #pragma unroll
      for (int d = 0; d < 4; ++d) {
        O[m][d] = __builtin_amdgcn_mfma_f32_16x16x32_bf16(pf[m][0], vf[d][0], O[m][d], 0, 0, 0);
        O[m][d] = __builtin_amdgcn_mfma_f32_16x16x32_bf16(pf[m][1], vf[d][1], O[m][d], 0, 0, 0);
      }
  };

  const int nkvt = (c >> 1) + 1;
  for (int kvt = 0; kvt < nkvt - 1; ++kvt) step(kvt * 64, FalseT{});
  step((nkvt - 1) * 64, TrueT{});

  // --- final l reduce + output ---
  #pragma unroll
  for (int off = 1; off < 16; off <<= 1)
    #pragma unroll
    for (int m = 0; m < 2; ++m)
      #pragma unroll
      for (int r = 0; r < 4; ++r)
        lpart[m][r] += __shfl_xor(lpart[m][r], off);
  #pragma unroll
  for (int m = 0; m < 2; ++m)
    #pragma unroll
    for (int r = 0; r < 4; ++r) {
      float inv = 1.0f / lpart[m][r];
      int qpos = q0 + m * 16 + lg * 4 + r;
      #pragma unroll
      for (int d = 0; d < 4; ++d)
        Aout[(size_t)(b * SSEQ + qpos) * DIME + h * HD + d * 16 + lr] = f2b(O[m][d][r] * inv);
    }
}

extern "C" void kernel_launch(void* const* d_in, const int* in_sizes, int n_in,
                              void* d_out, int out_size, void* d_ws, size_t ws_size,
                              hipStream_t stream) {
  const float* x     = (const float*)d_in[0];
  const float* w_qkv = (const float*)d_in[1];
  const float* w_out = (const float*)d_in[2];
  float* out = (float*)d_out;

  char* ws = (char*)d_ws;
  size_t off = 0;
  auto alloc = [&](size_t bytes) -> void* {
    void* p = ws + off;
    off += (bytes + 255) & ~(size_t)255;
    return p;
  };
  short* xb    = (short*)alloc((size_t)MTOT * DIME * 2);
  short* wqkvT = (short*)alloc((size_t)PACKED * DIME * 2);
  short* woutT = (short*)alloc((size_t)DIME * DIME * 2);
  short* qkv   = (short*)alloc((size_t)MTOT * PACKED * 2);
  short* Qb    = (short*)alloc((size_t)BB * NH * SSEQ * HD * 2);
  short* Kb    = (short*)alloc((size_t)BB * NKV * SSEQ * HD * 2);
  short* VTb   = (short*)alloc((size_t)BB * NKV * HD * SSEQ * 2);
  float* ctab  = (float*)alloc((size_t)SSEQ * 32 * 4);
  float* stab  = (float*)alloc((size_t)SSEQ * 32 * 4);
  short* attnb = qkv;  // reuse: qkv dead after rope_split + v_transpose

  cast_bf16<<<2048, 256, 0, stream>>>(x, xb, MTOT * DIME / 4);
  transpose_cast<<<dim3(PACKED / 32, DIME / 32), dim3(32, 8), 0, stream>>>(w_qkv, wqkvT, DIME, PACKED);
  transpose_cast<<<dim3(DIME / 32, DIME / 32), dim3(32, 8), 0, stream>>>(w_out, woutT, DIME, DIME);
  rope_table<<<(SSEQ * 32) / 256, 256, 0, stream>>>(ctab, stab);

  gemm_bt<true><<<dim3(MTOT / 128, PACKED / 128), 256, 0, stream>>>(xb, wqkvT, qkv, MTOT, PACKED, DIME);

  rope_split<<<(BB * SSEQ * 40) / 4, 256, 0, stream>>>(qkv, ctab, stab, Qb, Kb);
  v_transpose<<<BB * NKV * (SSEQ / 64), 256, 0, stream>>>(qkv, VTb);

  attn_fwd<<<1024, 256, 0, stream>>>(Qb, Kb, VTb, attnb);

  gemm_bt<false><<<dim3(MTOT / 128, DIME / 128), 256, 0, stream>>>(attnb, woutT, out, MTOT, DIME, DIME);
}

// Round 5
// 301.029 us; speedup vs baseline: 1.4140x; 1.4140x over previous
//
#include <hip/hip_runtime.h>
#include <hip/hip_bf16.h>
#include <cstdint>
#include <cstddef>

#define DIME 2048
#define NH 32
#define NKV 8
#define HD 64
#define BB 2
#define SSEQ 2048
#define PACKED (DIME + 2*NKV*HD)   // 3072
#define MTOT (BB*SSEQ)             // 4096

typedef __attribute__((ext_vector_type(8))) short bf16x8;
typedef __attribute__((ext_vector_type(4))) float f32x4;

struct FalseT { static constexpr bool value = false; };
struct TrueT  { static constexpr bool value = true;  };

__device__ __forceinline__ short f2b(float f) {
  unsigned u = __builtin_bit_cast(unsigned, f);
  u += 0x7fffu + ((u >> 16) & 1u);
  return (short)(u >> 16);
}
__device__ __forceinline__ float b2f(short s) {
  unsigned u = ((unsigned)(unsigned short)s) << 16;
  return __builtin_bit_cast(float, u);
}

__device__ __forceinline__ void gload_lds16(const void* g, void* l) {
  __builtin_amdgcn_global_load_lds(
      (const __attribute__((address_space(1))) void*)g,
      (__attribute__((address_space(3))) void*)l, 16, 0, 0);
}

// ---------------- cast fp32 -> bf16 (vectorized) ----------------
__global__ __launch_bounds__(256) void cast_bf16(const float* __restrict__ in,
                                                 short* __restrict__ out, int n4) {
  int i = blockIdx.x * blockDim.x + threadIdx.x;
  int stride = gridDim.x * blockDim.x;
  for (; i < n4; i += stride) {
    float4 v = ((const float4*)in)[i];
    short4 o;
    o.x = f2b(v.x); o.y = f2b(v.y); o.z = f2b(v.z); o.w = f2b(v.w);
    ((short4*)out)[i] = o;
  }
}

// ---------------- transpose + cast: in fp32 [R][C] -> out bf16 [C][R] ----------------
__global__ __launch_bounds__(256) void transpose_cast(const float* __restrict__ in,
                                                      short* __restrict__ out,
                                                      int R, int C) {
  __shared__ float tile[32][33];
  int bx = blockIdx.x * 32;
  int by = blockIdx.y * 32;
  int tx = threadIdx.x;
  int ty = threadIdx.y;
  #pragma unroll
  for (int j = 0; j < 4; ++j)
    tile[ty + j*8][tx] = in[(size_t)(by + ty + j*8) * C + bx + tx];
  __syncthreads();
  #pragma unroll
  for (int j = 0; j < 4; ++j)
    out[(size_t)(bx + ty + j*8) * R + by + tx] = f2b(tile[tx][ty + j*8]);
}

// ---------------- RoPE cos/sin table: [S][32] ----------------
__global__ __launch_bounds__(256) void rope_table(float* __restrict__ ctab,
                                                  float* __restrict__ stab) {
  int t = blockIdx.x * blockDim.x + threadIdx.x;
  int s = t >> 5, i = t & 31;
  float theta = 1.0f / powf(10000.0f, (float)(2 * i) * (1.0f / (float)HD));
  float ang = (float)s * theta;
  float sn, cs;
  sincosf(ang, &sn, &cs);
  ctab[t] = cs;
  stab[t] = sn;
}

// ---------------- GEMM: A[M][K] bf16, BT[N][K] bf16 -> C[M][N] ----------------
template<bool BF16_OUT>
__global__ __launch_bounds__(256) void gemm_bt(const short* __restrict__ A,
                                               const short* __restrict__ BT,
                                               void* __restrict__ Cout,
                                               int M, int N, int K) {
  __shared__ __align__(16) short As[128 * 32];
  __shared__ __align__(16) short Bs[128 * 32];
  const int tid = threadIdx.x;
  const int l = tid & 63, w = tid >> 6;
  const int lr = l & 15, lg = l >> 4;
  const int wm = w >> 1, wn = w & 1;
  const int bm = blockIdx.x * 128, bn = blockIdx.y * 128;

  f32x4 acc[4][4];
  #pragma unroll
  for (int m = 0; m < 4; ++m)
    #pragma unroll
    for (int n = 0; n < 4; ++n) {
      f32x4 z = {0.f, 0.f, 0.f, 0.f};
      acc[m][n] = z;
    }

  for (int k0 = 0; k0 < K; k0 += 32) {
    #pragma unroll
    for (int c = 0; c < 2; ++c) {
      const int cb = c * 256 + w * 64;
      const int chunk = cb + l;
      const int row = chunk >> 2, col = (chunk & 3) * 8;
      gload_lds16(A  + (size_t)(bm + row) * K + k0 + col, As + cb * 8);
      gload_lds16(BT + (size_t)(bn + row) * K + k0 + col, Bs + cb * 8);
    }
    __syncthreads();
    bf16x8 af[4], bf[4];
    #pragma unroll
    for (int m = 0; m < 4; ++m)
      af[m] = *(const bf16x8*)&As[(wm * 64 + m * 16 + lr) * 32 + lg * 8];
    #pragma unroll
    for (int n = 0; n < 4; ++n)
      bf[n] = *(const bf16x8*)&Bs[(wn * 64 + n * 16 + lr) * 32 + lg * 8];
    #pragma unroll
    for (int m = 0; m < 4; ++m)
      #pragma unroll
      for (int n = 0; n < 4; ++n)
        acc[m][n] = __builtin_amdgcn_mfma_f32_16x16x32_bf16(af[m], bf[n], acc[m][n], 0, 0, 0);
    __syncthreads();
  }

  #pragma unroll
  for (int m = 0; m < 4; ++m)
    #pragma unroll
    for (int n = 0; n < 4; ++n)
      #pragma unroll
      for (int r = 0; r < 4; ++r) {
        int row = bm + wm * 64 + m * 16 + lg * 4 + r;
        int col = bn + wn * 64 + n * 16 + lr;
        if (BF16_OUT)
          ((short*)Cout)[(size_t)row * N + col] = f2b(acc[m][n][r]);
        else
          ((float*)Cout)[(size_t)row * N + col] = acc[m][n][r];
      }
}

// ---------------- RoPE + split qkv -> Q [b][h][s][64] (PRESCALED), K [b][kvh][s][64] ----------------
__global__ __launch_bounds__(256) void rope_split(const short* __restrict__ qkv,
                                                  const float* __restrict__ ctab,
                                                  const float* __restrict__ stab,
                                                  short* __restrict__ Qo,
                                                  short* __restrict__ Ko) {
  int w = threadIdx.x >> 6, l = threadIdx.x & 63;
  int job = blockIdx.x * 4 + w;
  int b = job / (SSEQ * 40);
  int rem = job % (SSEQ * 40);
  int s = rem / 40;
  int hh = rem % 40;
  size_t base = (size_t)(b * SSEQ + s) * PACKED;
  int off = (hh < 32) ? (hh * HD + l) : (DIME + (hh - 32) * HD + l);
  float x = b2f(qkv[base + off]);
  float other = __shfl_xor(x, 1);
  int i = l >> 1;
  float cs = ctab[s * 32 + i], sn = stab[s * 32 + i];
  float o = (l & 1) ? (x * cs + other * sn) : (x * cs - other * sn);
  if (hh < 32) {
    o *= 0.180336880f;  // 0.125 * log2(e)
    Qo[((size_t)(b * NH + hh) * SSEQ + s) * HD + l] = f2b(o);
  } else {
    Ko[((size_t)(b * NKV + (hh - 32)) * SSEQ + s) * HD + l] = f2b(o);
  }
}

// ---------------- V transpose: qkv v-slice [s][64] -> VT [b][kvh][64][S] ----------------
__global__ __launch_bounds__(256) void v_transpose(const short* __restrict__ qkv,
                                                   short* __restrict__ VT) {
  __shared__ __align__(16) short tile[64][72];
  int bkv = blockIdx.x >> 5;
  int st = blockIdx.x & 31;
  int s0 = st * 64;
  int t = threadIdx.x;
  int srow = t >> 2, dq = (t & 3) * 16;
  size_t rowbase = (size_t)((bkv >> 3) * SSEQ + s0 + srow) * PACKED
                   + (DIME + NKV * HD) + (bkv & 7) * HD + dq;
  bf16x8 v0 = *(const bf16x8*)&qkv[rowbase];
  bf16x8 v1 = *(const bf16x8*)&qkv[rowbase + 8];
  #pragma unroll
  for (int j = 0; j < 8; ++j) tile[dq + j][srow] = v0[j];
  #pragma unroll
  for (int j = 0; j < 8; ++j) tile[dq + 8 + j][srow] = v1[j];
  __syncthreads();
  int d = t >> 2, sq = (t & 3) * 16;
  size_t obase = ((size_t)bkv * HD + d) * SSEQ + s0 + sq;
  *(bf16x8*)&VT[obase]     = *(const bf16x8*)&tile[d][sq];
  *(bf16x8*)&VT[obase + 8] = *(const bf16x8*)&tile[d][sq + 8];
}

// ---------------- Flash attention: causal GQA, v5 ----------------
// v4 grid layout (one chunk/wave, 1024 blocks, heavy-first) but with the
// default launch bounds: the (256,4) hint pinned VGPR to 64 and caused
// 80 MB of scratch spill traffic (round-4 counters). VGPR pressure is
// controlled structurally (in-place exp2, late V loads) instead.
__global__ __launch_bounds__(256) void attn_fwd(const short* __restrict__ Q,
                                                const short* __restrict__ K,
                                                const short* __restrict__ VT,
                                                short* __restrict__ Aout) {
  __shared__ __align__(16) short Plds[4][32 * 64];
  const int tid = threadIdx.x, l = tid & 63, w = tid >> 6;
  const int lr = l & 15, lg = l >> 4;
  const int c = 63 - (blockIdx.x >> 4);    // chunk index, heavy first
  const int bh = (blockIdx.x & 15) * 4 + w;
  const int b = bh >> 5, h = bh & 31, kvh = h >> 2;
  const short* Qp = Q + (size_t)(b * NH + h) * SSEQ * HD;
  const short* Kp = K + (size_t)(b * NKV + kvh) * SSEQ * HD;
  const short* Vp = VT + (size_t)(b * NKV + kvh) * HD * SSEQ;
  short* Pw = (short*)Plds[w];
  const int q0 = c * 32;

  bf16x8 qf[2][2];
  #pragma unroll
  for (int m = 0; m < 2; ++m)
    #pragma unroll
    for (int kh = 0; kh < 2; ++kh)
      qf[m][kh] = *(const bf16x8*)&Qp[(size_t)(q0 + m * 16 + lr) * HD + kh * 32 + lg * 8];

  f32x4 O[2][4];
  #pragma unroll
  for (int m = 0; m < 2; ++m)
    #pragma unroll
    for (int d = 0; d < 4; ++d) { f32x4 z = {0.f,0.f,0.f,0.f}; O[m][d] = z; }
  float mrun[2][4], lpart[2][4];
  #pragma unroll
  for (int m = 0; m < 2; ++m)
    #pragma unroll
    for (int r = 0; r < 4; ++r) { mrun[m][r] = -3e38f; lpart[m][r] = 0.f; }

  auto step = [&](int kv0, auto diag_tag) {
    constexpr bool DIAG = decltype(diag_tag)::value;
    bf16x8 kf[4][2];
    #pragma unroll
    for (int n = 0; n < 4; ++n)
      #pragma unroll
      for (int kh = 0; kh < 2; ++kh)
        kf[n][kh] = *(const bf16x8*)&Kp[(size_t)(kv0 + n * 16 + lr) * HD + kh * 32 + lg * 8];
    // --- QK^T (scores already in exp2-domain via prescaled Q) ---
    f32x4 sacc[2][4];
    #pragma unroll
    for (int m = 0; m < 2; ++m)
      #pragma unroll
      for (int n = 0; n < 4; ++n) { f32x4 z = {0.f,0.f,0.f,0.f}; sacc[m][n] = z; }
    #pragma unroll
    for (int m = 0; m < 2; ++m)
      #pragma unroll
      for (int n = 0; n < 4; ++n) {
        sacc[m][n] = __builtin_amdgcn_mfma_f32_16x16x32_bf16(qf[m][0], kf[n][0], sacc[m][n], 0, 0, 0);
        sacc[m][n] = __builtin_amdgcn_mfma_f32_16x16x32_bf16(qf[m][1], kf[n][1], sacc[m][n], 0, 0, 0);
      }
    // --- mask (diag only, in place) + per-lane max ---
    float pmax[2][4];
    #pragma unroll
    for (int m = 0; m < 2; ++m)
      #pragma unroll
      for (int r = 0; r < 4; ++r) pmax[m][r] = -3e38f;
    #pragma unroll
    for (int m = 0; m < 2; ++m)
      #pragma unroll
      for (int n = 0; n < 4; ++n)
        #pragma unroll
        for (int r = 0; r < 4; ++r) {
          if (DIAG) {
            if ((kv0 + n * 16 + lr) > (q0 + m * 16 + lg * 4 + r)) sacc[m][n][r] = -3e38f;
          }
          pmax[m][r] = fmaxf(pmax[m][r], sacc[m][n][r]);
        }
    // --- defer-max: rescale only when per-lane max grew past threshold ---
    int ok = 1;
    #pragma unroll
    for (int m = 0; m < 2; ++m)
      #pragma unroll
      for (int r = 0; r < 4; ++r)
        ok &= (pmax[m][r] <= mrun[m][r] + 11.0f);
    if (!__all(ok)) {
      #pragma unroll
      for (int off = 1; off < 16; off <<= 1)
        #pragma unroll
        for (int m = 0; m < 2; ++m)
          #pragma unroll
          for (int r = 0; r < 4; ++r)
            pmax[m][r] = fmaxf(pmax[m][r], __shfl_xor(pmax[m][r], off));
      #pragma unroll
      for (int m = 0; m < 2; ++m)
        #pragma unroll
        for (int r = 0; r < 4; ++r) {
          float mn = fmaxf(mrun[m][r], pmax[m][r]);
          float corr = exp2f(mrun[m][r] - mn);
          mrun[m][r] = mn;
          lpart[m][r] *= corr;
          #pragma unroll
          for (int d = 0; d < 4; ++d) O[m][d][r] *= corr;
        }
    }
    // --- exp2 (in place) + P store (swizzled) + l partials ---
    #pragma unroll
    for (int m = 0; m < 2; ++m)
      #pragma unroll
      for (int r = 0; r < 4; ++r) {
        float ls = 0.f;
        #pragma unroll
        for (int n = 0; n < 4; ++n) {
          float e = exp2f(sacc[m][n][r] - mrun[m][r]);
          ls += e;
          int row = m * 16 + lg * 4 + r;
          int byte = (row * 64 + n * 16 + lr) * 2;
          byte ^= (row & 7) << 4;
          unsigned u = __builtin_bit_cast(unsigned, e);
          Pw[byte >> 1] = (short)((u + 0x8000u) >> 16);
        }
        lpart[m][r] += ls;
      }
    // --- PV (V fragments loaded here, not earlier: bounds live VGPRs) ---
    bf16x8 pf[2][2];
    #pragma unroll
    for (int m = 0; m < 2; ++m)
      #pragma unroll
      for (int kh = 0; kh < 2; ++kh) {
        int byte = ((m * 16 + lr) * 64 + kh * 32 + lg * 8) * 2;
        byte ^= (lr & 7) << 4;
        pf[m][kh] = *(const bf16x8*)&Pw[byte >> 1];
      }
    bf16x8 vf[4][2];
    #pragma unroll
    for (int d = 0; d < 4; ++d)
      #pragma unroll
      for (int kh = 0; kh < 2; ++kh)
        vf[d][kh] = *(const bf16x8*)&Vp[(size_t)(d * 16 + lr) * SSEQ + kv0 + kh * 32 + lg * 8];
    #pragma unroll
    for (int m = 0; m < 2; ++m)
      #pragma unroll
      for (int d = 0; d < 4; ++d) {
        O[m][d] = __builtin_amdgcn_mfma_f32_16x16x32_bf16(pf[m][0], vf[d][0], O[m][d], 0, 0, 0);
        O[m][d] = __builtin_amdgcn_mfma_f32_16x16x32_bf16(pf[m][1], vf[d][1], O[m][d], 0, 0, 0);
      }
  };

  const int nkvt = (c >> 1) + 1;
  for (int kvt = 0; kvt < nkvt - 1; ++kvt) step(kvt * 64, FalseT{});
  step((nkvt - 1) * 64, TrueT{});

  // --- final l reduce + output ---
  #pragma unroll
  for (int off = 1; off < 16; off <<= 1)
    #pragma unroll
    for (int m = 0; m < 2; ++m)
      #pragma unroll
      for (int r = 0; r < 4; ++r)
        lpart[m][r] += __shfl_xor(lpart[m][r], off);
  #pragma unroll
  for (int m = 0; m < 2; ++m)
    #pragma unroll
    for (int r = 0; r < 4; ++r) {
      float inv = 1.0f / lpart[m][r];
      int qpos = q0 + m * 16 + lg * 4 + r;
      #pragma unroll
      for (int d = 0; d < 4; ++d)
        Aout[(size_t)(b * SSEQ + qpos) * DIME + h * HD + d * 16 + lr] = f2b(O[m][d][r] * inv);
    }
}

extern "C" void kernel_launch(void* const* d_in, const int* in_sizes, int n_in,
                              void* d_out, int out_size, void* d_ws, size_t ws_size,
                              hipStream_t stream) {
  const float* x     = (const float*)d_in[0];
  const float* w_qkv = (const float*)d_in[1];
  const float* w_out = (const float*)d_in[2];
  float* out = (float*)d_out;

  char* ws = (char*)d_ws;
  size_t off = 0;
  auto alloc = [&](size_t bytes) -> void* {
    void* p = ws + off;
    off += (bytes + 255) & ~(size_t)255;
    return p;
  };
  short* xb    = (short*)alloc((size_t)MTOT * DIME * 2);
  short* wqkvT = (short*)alloc((size_t)PACKED * DIME * 2);
  short* woutT = (short*)alloc((size_t)DIME * DIME * 2);
  short* qkv   = (short*)alloc((size_t)MTOT * PACKED * 2);
  short* Qb    = (short*)alloc((size_t)BB * NH * SSEQ * HD * 2);
  short* Kb    = (short*)alloc((size_t)BB * NKV * SSEQ * HD * 2);
  short* VTb   = (short*)alloc((size_t)BB * NKV * HD * SSEQ * 2);
  float* ctab  = (float*)alloc((size_t)SSEQ * 32 * 4);
  float* stab  = (float*)alloc((size_t)SSEQ * 32 * 4);
  short* attnb = qkv;  // reuse: qkv dead after rope_split + v_transpose

  cast_bf16<<<2048, 256, 0, stream>>>(x, xb, MTOT * DIME / 4);
  transpose_cast<<<dim3(PACKED / 32, DIME / 32), dim3(32, 8), 0, stream>>>(w_qkv, wqkvT, DIME, PACKED);
  transpose_cast<<<dim3(DIME / 32, DIME / 32), dim3(32, 8), 0, stream>>>(w_out, woutT, DIME, DIME);
  rope_table<<<(SSEQ * 32) / 256, 256, 0, stream>>>(ctab, stab);

  gemm_bt<true><<<dim3(MTOT / 128, PACKED / 128), 256, 0, stream>>>(xb, wqkvT, qkv, MTOT, PACKED, DIME);

  rope_split<<<(BB * SSEQ * 40) / 4, 256, 0, stream>>>(qkv, ctab, stab, Qb, Kb);
  v_transpose<<<BB * NKV * (SSEQ / 64), 256, 0, stream>>>(qkv, VTb);

  attn_fwd<<<1024, 256, 0, stream>>>(Qb, Kb, VTb, attnb);

  gemm_bt<false><<<dim3(MTOT / 128, DIME / 128), 256, 0, stream>>>(attnb, woutT, out, MTOT, DIME, DIME);
}

// Round 6
// 295.528 us; speedup vs baseline: 1.4404x; 1.0186x over previous
//
#include <hip/hip_runtime.h>
#include <hip/hip_bf16.h>
#include <cstdint>
#include <cstddef>

#define DIME 2048
#define NH 32
#define NKV 8
#define HD 64
#define BB 2
#define SSEQ 2048
#define PACKED (DIME + 2*NKV*HD)   // 3072
#define MTOT (BB*SSEQ)             // 4096

typedef __attribute__((ext_vector_type(8))) short bf16x8;
typedef __attribute__((ext_vector_type(4))) float f32x4;
typedef __attribute__((ext_vector_type(16))) float f32x16;
typedef __attribute__((ext_vector_type(4))) unsigned u32x4;

struct FalseT { static constexpr bool value = false; };
struct TrueT  { static constexpr bool value = true;  };

__device__ __forceinline__ short f2b(float f) {
  unsigned u = __builtin_bit_cast(unsigned, f);
  u += 0x7fffu + ((u >> 16) & 1u);
  return (short)(u >> 16);
}
__device__ __forceinline__ float b2f(short s) {
  unsigned u = ((unsigned)(unsigned short)s) << 16;
  return __builtin_bit_cast(float, u);
}
// pack two f32 -> one u32 of 2 bf16 (low = lo, high = hi)
__device__ __forceinline__ unsigned cvt_pk(float lo, float hi) {
  unsigned r;
  asm("v_cvt_pk_bf16_f32 %0, %1, %2" : "=v"(r) : "v"(lo), "v"(hi));
  return r;
}

__device__ __forceinline__ void gload_lds16(const void* g, void* l) {
  __builtin_amdgcn_global_load_lds(
      (const __attribute__((address_space(1))) void*)g,
      (__attribute__((address_space(3))) void*)l, 16, 0, 0);
}

// ---------------- cast fp32 -> bf16 (vectorized) ----------------
__global__ __launch_bounds__(256) void cast_bf16(const float* __restrict__ in,
                                                 short* __restrict__ out, int n4) {
  int i = blockIdx.x * blockDim.x + threadIdx.x;
  int stride = gridDim.x * blockDim.x;
  for (; i < n4; i += stride) {
    float4 v = ((const float4*)in)[i];
    short4 o;
    o.x = f2b(v.x); o.y = f2b(v.y); o.z = f2b(v.z); o.w = f2b(v.w);
    ((short4*)out)[i] = o;
  }
}

// ---------------- transpose + cast: in fp32 [R][C] -> out bf16 [C][R] ----------------
__global__ __launch_bounds__(256) void transpose_cast(const float* __restrict__ in,
                                                      short* __restrict__ out,
                                                      int R, int C) {
  __shared__ float tile[32][33];
  int bx = blockIdx.x * 32;
  int by = blockIdx.y * 32;
  int tx = threadIdx.x;
  int ty = threadIdx.y;
  #pragma unroll
  for (int j = 0; j < 4; ++j)
    tile[ty + j*8][tx] = in[(size_t)(by + ty + j*8) * C + bx + tx];
  __syncthreads();
  #pragma unroll
  for (int j = 0; j < 4; ++j)
    out[(size_t)(bx + ty + j*8) * R + by + tx] = f2b(tile[tx][ty + j*8]);
}

// ---------------- RoPE cos/sin table: [S][32] ----------------
__global__ __launch_bounds__(256) void rope_table(float* __restrict__ ctab,
                                                  float* __restrict__ stab) {
  int t = blockIdx.x * blockDim.x + threadIdx.x;
  int s = t >> 5, i = t & 31;
  float theta = 1.0f / powf(10000.0f, (float)(2 * i) * (1.0f / (float)HD));
  float ang = (float)s * theta;
  float sn, cs;
  sincosf(ang, &sn, &cs);
  ctab[t] = cs;
  stab[t] = sn;
}

// ---------------- GEMM: A[M][K] bf16, BT[N][K] bf16 -> C[M][N] ----------------
template<bool BF16_OUT>
__global__ __launch_bounds__(256) void gemm_bt(const short* __restrict__ A,
                                               const short* __restrict__ BT,
                                               void* __restrict__ Cout,
                                               int M, int N, int K) {
  __shared__ __align__(16) short As[128 * 32];
  __shared__ __align__(16) short Bs[128 * 32];
  const int tid = threadIdx.x;
  const int l = tid & 63, w = tid >> 6;
  const int lr = l & 15, lg = l >> 4;
  const int wm = w >> 1, wn = w & 1;
  const int bm = blockIdx.x * 128, bn = blockIdx.y * 128;

  f32x4 acc[4][4];
  #pragma unroll
  for (int m = 0; m < 4; ++m)
    #pragma unroll
    for (int n = 0; n < 4; ++n) {
      f32x4 z = {0.f, 0.f, 0.f, 0.f};
      acc[m][n] = z;
    }

  for (int k0 = 0; k0 < K; k0 += 32) {
    #pragma unroll
    for (int c = 0; c < 2; ++c) {
      const int cb = c * 256 + w * 64;
      const int chunk = cb + l;
      const int row = chunk >> 2, col = (chunk & 3) * 8;
      gload_lds16(A  + (size_t)(bm + row) * K + k0 + col, As + cb * 8);
      gload_lds16(BT + (size_t)(bn + row) * K + k0 + col, Bs + cb * 8);
    }
    __syncthreads();
    bf16x8 af[4], bf[4];
    #pragma unroll
    for (int m = 0; m < 4; ++m)
      af[m] = *(const bf16x8*)&As[(wm * 64 + m * 16 + lr) * 32 + lg * 8];
    #pragma unroll
    for (int n = 0; n < 4; ++n)
      bf[n] = *(const bf16x8*)&Bs[(wn * 64 + n * 16 + lr) * 32 + lg * 8];
    #pragma unroll
    for (int m = 0; m < 4; ++m)
      #pragma unroll
      for (int n = 0; n < 4; ++n)
        acc[m][n] = __builtin_amdgcn_mfma_f32_16x16x32_bf16(af[m], bf[n], acc[m][n], 0, 0, 0);
    __syncthreads();
  }

  #pragma unroll
  for (int m = 0; m < 4; ++m)
    #pragma unroll
    for (int n = 0; n < 4; ++n)
      #pragma unroll
      for (int r = 0; r < 4; ++r) {
        int row = bm + wm * 64 + m * 16 + lg * 4 + r;
        int col = bn + wn * 64 + n * 16 + lr;
        if (BF16_OUT)
          ((short*)Cout)[(size_t)row * N + col] = f2b(acc[m][n][r]);
        else
          ((float*)Cout)[(size_t)row * N + col] = acc[m][n][r];
      }
}

// ---------------- RoPE + split qkv -> Q [b][h][s][64] (PRESCALED), K [b][kvh][s][64] ----------------
__global__ __launch_bounds__(256) void rope_split(const short* __restrict__ qkv,
                                                  const float* __restrict__ ctab,
                                                  const float* __restrict__ stab,
                                                  short* __restrict__ Qo,
                                                  short* __restrict__ Ko) {
  int w = threadIdx.x >> 6, l = threadIdx.x & 63;
  int job = blockIdx.x * 4 + w;
  int b = job / (SSEQ * 40);
  int rem = job % (SSEQ * 40);
  int s = rem / 40;
  int hh = rem % 40;
  size_t base = (size_t)(b * SSEQ + s) * PACKED;
  int off = (hh < 32) ? (hh * HD + l) : (DIME + (hh - 32) * HD + l);
  float x = b2f(qkv[base + off]);
  float other = __shfl_xor(x, 1);
  int i = l >> 1;
  float cs = ctab[s * 32 + i], sn = stab[s * 32 + i];
  float o = (l & 1) ? (x * cs + other * sn) : (x * cs - other * sn);
  if (hh < 32) {
    o *= 0.180336880f;  // 0.125 * log2(e)
    Qo[((size_t)(b * NH + hh) * SSEQ + s) * HD + l] = f2b(o);
  } else {
    Ko[((size_t)(b * NKV + (hh - 32)) * SSEQ + s) * HD + l] = f2b(o);
  }
}

// ---------------- V transpose: qkv v-slice [s][64] -> VT [b][kvh][64][S] ----------------
__global__ __launch_bounds__(256) void v_transpose(const short* __restrict__ qkv,
                                                   short* __restrict__ VT) {
  __shared__ __align__(16) short tile[64][72];
  int bkv = blockIdx.x >> 5;
  int st = blockIdx.x & 31;
  int s0 = st * 64;
  int t = threadIdx.x;
  int srow = t >> 2, dq = (t & 3) * 16;
  size_t rowbase = (size_t)((bkv >> 3) * SSEQ + s0 + srow) * PACKED
                   + (DIME + NKV * HD) + (bkv & 7) * HD + dq;
  bf16x8 v0 = *(const bf16x8*)&qkv[rowbase];
  bf16x8 v1 = *(const bf16x8*)&qkv[rowbase + 8];
  #pragma unroll
  for (int j = 0; j < 8; ++j) tile[dq + j][srow] = v0[j];
  #pragma unroll
  for (int j = 0; j < 8; ++j) tile[dq + 8 + j][srow] = v1[j];
  __syncthreads();
  int d = t >> 2, sq = (t & 3) * 16;
  size_t obase = ((size_t)bkv * HD + d) * SSEQ + s0 + sq;
  *(bf16x8*)&VT[obase]     = *(const bf16x8*)&tile[d][sq];
  *(bf16x8*)&VT[obase + 8] = *(const bf16x8*)&tile[d][sq + 8];
}

// ---------------- Flash attention: causal GQA, v6 ----------------
// Swapped QK^T (m214/T12 structure): mfma_32x32x16(K, Q) puts the score tile
// transposed so each lane owns ONE q-row (lane&31) and 32 kv values in regs.
// Softmax fully in-register (in-lane max/sum + one shfl_xor(32)); the P->PV
// A-fragment is built with v_cvt_pk_bf16_f32 + half-swap exchange. No LDS.
// C-layout (m74/m101): col=lane&31, row=(r&3)+8*(r>>2)+4*(lane>>5).
__global__ __launch_bounds__(256) void attn_fwd(const short* __restrict__ Q,
                                                const short* __restrict__ K,
                                                const short* __restrict__ VT,
                                                short* __restrict__ Aout) {
  const int tid = threadIdx.x, l = tid & 63, w = tid >> 6;
  const int l31 = l & 31;
  const int hi = l >> 5;                   // lane half (k-chunk / crow +4)
  const int c = 63 - (blockIdx.x >> 4);    // chunk index, heavy first
  const int bh = (blockIdx.x & 15) * 4 + w;
  const int b = bh >> 5, hh = bh & 31, kvh = hh >> 2;
  const short* Qp = Q + (size_t)(b * NH + hh) * SSEQ * HD;
  const short* Kp = K + (size_t)(b * NKV + kvh) * SSEQ * HD;
  const short* Vp = VT + (size_t)(b * NKV + kvh) * HD * SSEQ;
  const int q0 = c * 32;
  const int qrow = q0 + l31;

  // Q as B-operand: col = lane&31 = q-row, k = hi*8 + e, 4 K-steps over HD
  bf16x8 qf[4];
  #pragma unroll
  for (int ks = 0; ks < 4; ++ks)
    qf[ks] = *(const bf16x8*)&Qp[(size_t)qrow * HD + ks * 16 + hi * 8];

  f32x16 O0, O1;
  #pragma unroll
  for (int r = 0; r < 16; ++r) { O0[r] = 0.f; O1[r] = 0.f; }
  float mrun = -3.0e38f, lsum = 0.f;

  auto step = [&](int kv0, auto diag_tag) {
    constexpr bool DIAG = decltype(diag_tag)::value;
    // K as A-operand: row = lane&31 = kv row, k = hi*8 + e
    bf16x8 kf0[4], kf1[4];
    #pragma unroll
    for (int ks = 0; ks < 4; ++ks) {
      kf0[ks] = *(const bf16x8*)&Kp[(size_t)(kv0 + l31) * HD + ks * 16 + hi * 8];
      kf1[ks] = *(const bf16x8*)&Kp[(size_t)(kv0 + 32 + l31) * HD + ks * 16 + hi * 8];
    }
    // QK^T: sacc[n][r] = S[q = l31][kv = kv0 + n*32 + (r&3)+8*(r>>2)+4*hi]
    f32x16 sacc[2];
    #pragma unroll
    for (int r = 0; r < 16; ++r) { sacc[0][r] = 0.f; sacc[1][r] = 0.f; }
    #pragma unroll
    for (int ks = 0; ks < 4; ++ks) {
      sacc[0] = __builtin_amdgcn_mfma_f32_32x32x16_bf16(kf0[ks], qf[ks], sacc[0], 0, 0, 0);
      sacc[1] = __builtin_amdgcn_mfma_f32_32x32x16_bf16(kf1[ks], qf[ks], sacc[1], 0, 0, 0);
    }
    // mask (diag only) + per-lane max over this lane's 32 kv values
    float pm = -3.0e38f;
    #pragma unroll
    for (int n = 0; n < 2; ++n)
      #pragma unroll
      for (int r = 0; r < 16; ++r) {
        if (DIAG) {
          int kvg = kv0 + n * 32 + ((r & 3) + 8 * (r >> 2)) + 4 * hi;
          if (kvg > qrow) sacc[n][r] = -3.0e38f;
        }
        pm = fmaxf(pm, sacc[n][r]);
      }
    // full row max = in-lane max + partner-half swap
    pm = fmaxf(pm, __shfl_xor(pm, 32));
    // defer-max: rescale only when row max grew past threshold (log2 units)
    if (!__all(pm <= mrun + 11.0f)) {
      float mn = fmaxf(mrun, pm);
      float corr = exp2f(mrun - mn);
      mrun = mn;
      lsum *= corr;
      #pragma unroll
      for (int r = 0; r < 16; ++r) {
        float cq = __shfl(corr, ((r & 3) + 8 * (r >> 2)) + 4 * hi);
        O0[r] *= cq;
        O1[r] *= cq;
      }
    }
    // exp2 in place + in-lane partial sum
    #pragma unroll
    for (int n = 0; n < 2; ++n)
      #pragma unroll
      for (int r = 0; r < 16; ++r) {
        float e = exp2f(sacc[n][r] - mrun);
        sacc[n][r] = e;
        lsum += e;
      }
    // pack P into PV A-fragments: pa[ks] holds A[row=q=l31][k=hi*8+e],
    // kv = ks*16 + hi*8 + e.  Derived exchange (m214 "one swap, two words"):
    // pair (pk(p[r0],p[r0+1]), pk(p[r0+4],p[r0+5])) -> (e01, e45) via half-swap.
    bf16x8 pa[4];
    #pragma unroll
    for (int n = 0; n < 2; ++n)
      #pragma unroll
      for (int s = 0; s < 2; ++s) {
        const int r0 = s * 8;
        unsigned A1 = cvt_pk(sacc[n][r0 + 0], sacc[n][r0 + 1]);
        unsigned B1 = cvt_pk(sacc[n][r0 + 4], sacc[n][r0 + 5]);
        unsigned A2 = cvt_pk(sacc[n][r0 + 2], sacc[n][r0 + 3]);
        unsigned B2 = cvt_pk(sacc[n][r0 + 6], sacc[n][r0 + 7]);
        unsigned shB1 = (unsigned)__shfl_xor((int)B1, 32);
        unsigned shA1 = (unsigned)__shfl_xor((int)A1, 32);
        unsigned shB2 = (unsigned)__shfl_xor((int)B2, 32);
        unsigned shA2 = (unsigned)__shfl_xor((int)A2, 32);
        u32x4 words;
        words[0] = hi ? shB1 : A1;   // e0,e1
        words[1] = hi ? shB2 : A2;   // e2,e3
        words[2] = hi ? B1 : shA1;   // e4,e5
        words[3] = hi ? B2 : shA2;   // e6,e7
        pa[n * 2 + s] = __builtin_bit_cast(bf16x8, words);
      }
    // V as B-operand: col = lane&31 = d, k = kv chunk; from VT [d][S]
    bf16x8 vf0[4], vf1[4];
    #pragma unroll
    for (int ks = 0; ks < 4; ++ks) {
      vf0[ks] = *(const bf16x8*)&Vp[(size_t)l31 * SSEQ + kv0 + ks * 16 + hi * 8];
      vf1[ks] = *(const bf16x8*)&Vp[(size_t)(32 + l31) * SSEQ + kv0 + ks * 16 + hi * 8];
    }
    #pragma unroll
    for (int ks = 0; ks < 4; ++ks) {
      O0 = __builtin_amdgcn_mfma_f32_32x32x16_bf16(pa[ks], vf0[ks], O0, 0, 0, 0);
      O1 = __builtin_amdgcn_mfma_f32_32x32x16_bf16(pa[ks], vf1[ks], O1, 0, 0, 0);
    }
  };

  const int nkvt = (c >> 1) + 1;
  for (int kvt = 0; kvt < nkvt - 1; ++kvt) step(kvt * 64, FalseT{});
  step((nkvt - 1) * 64, TrueT{});

  // final l: add partner half, then scale + output
  lsum += __shfl_xor(lsum, 32);
  float inv = 1.0f / lsum;
  #pragma unroll
  for (int r = 0; r < 16; ++r) {
    int crow = (r & 3) + 8 * (r >> 2) + 4 * hi;
    float iq = __shfl(inv, crow);
    int qg = q0 + crow;
    size_t base = (size_t)(b * SSEQ + qg) * DIME + hh * HD;
    Aout[base + l31]      = f2b(O0[r] * iq);
    Aout[base + 32 + l31] = f2b(O1[r] * iq);
  }
}

extern "C" void kernel_launch(void* const* d_in, const int* in_sizes, int n_in,
                              void* d_out, int out_size, void* d_ws, size_t ws_size,
                              hipStream_t stream) {
  const float* x     = (const float*)d_in[0];
  const float* w_qkv = (const float*)d_in[1];
  const float* w_out = (const float*)d_in[2];
  float* out = (float*)d_out;

  char* ws = (char*)d_ws;
  size_t off = 0;
  auto alloc = [&](size_t bytes) -> void* {
    void* p = ws + off;
    off += (bytes + 255) & ~(size_t)255;
    return p;
  };
  short* xb    = (short*)alloc((size_t)MTOT * DIME * 2);
  short* wqkvT = (short*)alloc((size_t)PACKED * DIME * 2);
  short* woutT = (short*)alloc((size_t)DIME * DIME * 2);
  short* qkv   = (short*)alloc((size_t)MTOT * PACKED * 2);
  short* Qb    = (short*)alloc((size_t)BB * NH * SSEQ * HD * 2);
  short* Kb    = (short*)alloc((size_t)BB * NKV * SSEQ * HD * 2);
  short* VTb   = (short*)alloc((size_t)BB * NKV * HD * SSEQ * 2);
  float* ctab  = (float*)alloc((size_t)SSEQ * 32 * 4);
  float* stab  = (float*)alloc((size_t)SSEQ * 32 * 4);
  short* attnb = qkv;  // reuse: qkv dead after rope_split + v_transpose

  cast_bf16<<<2048, 256, 0, stream>>>(x, xb, MTOT * DIME / 4);
  transpose_cast<<<dim3(PACKED / 32, DIME / 32), dim3(32, 8), 0, stream>>>(w_qkv, wqkvT, DIME, PACKED);
  transpose_cast<<<dim3(DIME / 32, DIME / 32), dim3(32, 8), 0, stream>>>(w_out, woutT, DIME, DIME);
  rope_table<<<(SSEQ * 32) / 256, 256, 0, stream>>>(ctab, stab);

  gemm_bt<true><<<dim3(MTOT / 128, PACKED / 128), 256, 0, stream>>>(xb, wqkvT, qkv, MTOT, PACKED, DIME);

  rope_split<<<(BB * SSEQ * 40) / 4, 256, 0, stream>>>(qkv, ctab, stab, Qb, Kb);
  v_transpose<<<BB * NKV * (SSEQ / 64), 256, 0, stream>>>(qkv, VTb);

  attn_fwd<<<1024, 256, 0, stream>>>(Qb, Kb, VTb, attnb);

  gemm_bt<false><<<dim3(MTOT / 128, DIME / 128), 256, 0, stream>>>(attnb, woutT, out, MTOT, DIME, DIME);
}

// Round 7
// 268.143 us; speedup vs baseline: 1.5875x; 1.1021x over previous
//
#include <hip/hip_runtime.h>
#include <hip/hip_bf16.h>
#include <cstdint>
#include <cstddef>

#define DIME 2048
#define NH 32
#define NKV 8
#define HD 64
#define BB 2
#define SSEQ 2048
#define PACKED (DIME + 2*NKV*HD)   // 3072
#define MTOT (BB*SSEQ)             // 4096

typedef __attribute__((ext_vector_type(8))) short bf16x8;
typedef __attribute__((ext_vector_type(4))) float f32x4;
typedef __attribute__((ext_vector_type(16))) float f32x16;
typedef __attribute__((ext_vector_type(4))) unsigned u32x4;

struct FalseT { static constexpr bool value = false; };
struct TrueT  { static constexpr bool value = true;  };

__device__ __forceinline__ short f2b(float f) {
  unsigned u = __builtin_bit_cast(unsigned, f);
  u += 0x7fffu + ((u >> 16) & 1u);
  return (short)(u >> 16);
}
__device__ __forceinline__ float b2f(short s) {
  unsigned u = ((unsigned)(unsigned short)s) << 16;
  return __builtin_bit_cast(float, u);
}
__device__ __forceinline__ unsigned cvt_pk(float lo, float hi) {
  unsigned r;
  asm("v_cvt_pk_bf16_f32 %0, %1, %2" : "=v"(r) : "v"(lo), "v"(hi));
  return r;
}

__device__ __forceinline__ void gload_lds16(const void* g, void* l) {
  __builtin_amdgcn_global_load_lds(
      (const __attribute__((address_space(1))) void*)g,
      (__attribute__((address_space(3))) void*)l, 16, 0, 0);
}

// ---------------- cast fp32 -> bf16 (vectorized) ----------------
__global__ __launch_bounds__(256) void cast_bf16(const float* __restrict__ in,
                                                 short* __restrict__ out, int n4) {
  int i = blockIdx.x * blockDim.x + threadIdx.x;
  int stride = gridDim.x * blockDim.x;
  for (; i < n4; i += stride) {
    float4 v = ((const float4*)in)[i];
    short4 o;
    o.x = f2b(v.x); o.y = f2b(v.y); o.z = f2b(v.z); o.w = f2b(v.w);
    ((short4*)out)[i] = o;
  }
}

// ---------------- transpose + cast: in fp32 [R][C] -> out bf16 [C][R] ----------------
__global__ __launch_bounds__(256) void transpose_cast(const float* __restrict__ in,
                                                      short* __restrict__ out,
                                                      int R, int C) {
  __shared__ float tile[32][33];
  int bx = blockIdx.x * 32;
  int by = blockIdx.y * 32;
  int tx = threadIdx.x;
  int ty = threadIdx.y;
  #pragma unroll
  for (int j = 0; j < 4; ++j)
    tile[ty + j*8][tx] = in[(size_t)(by + ty + j*8) * C + bx + tx];
  __syncthreads();
  #pragma unroll
  for (int j = 0; j < 4; ++j)
    out[(size_t)(bx + ty + j*8) * R + by + tx] = f2b(tile[tx][ty + j*8]);
}

// ---------------- RoPE cos/sin table: [S][32] ----------------
__global__ __launch_bounds__(256) void rope_table(float* __restrict__ ctab,
                                                  float* __restrict__ stab) {
  int t = blockIdx.x * blockDim.x + threadIdx.x;
  int s = t >> 5, i = t & 31;
  float theta = 1.0f / powf(10000.0f, (float)(2 * i) * (1.0f / (float)HD));
  float ang = (float)s * theta;
  float sn, cs;
  sincosf(ang, &sn, &cs);
  ctab[t] = cs;
  stab[t] = sn;
}

// ---------------- GEMM v2: counted-vmcnt pipeline (T3+T4+T5) ----------------
// A[M][K] bf16, BT[N][K] bf16 -> C[M][N].  128x128 tile, BK=64, 4 waves.
// LDS 64 KB: 2 dbuf x {A,B} x 2 k-subtiles, each subtile [128 rows][32 cols]
// with m97's 64B-row layout (fragment reads = 64 distinct contiguous 16B
// slots -> conflict-free; staging stays linear for global_load_lds, sources
// pre-permuted - rule #21 both-sides-or-neither).
// Loop: ds_read frags -> lgkmcnt(0)+barrier -> STAGE t+2 -> MFMA (setprio)
//       -> vmcnt(8) [counted, never 0 in-loop] -> barrier.
template<bool BF16_OUT>
__global__ __launch_bounds__(256) void gemm_bt(const short* __restrict__ A,
                                               const short* __restrict__ BT,
                                               void* __restrict__ Cout,
                                               int M, int N, int K) {
  // [dbuf][A=0/B=1][ksub][512 slots * 8 shorts]
  __shared__ __align__(16) short lds[2][2][2][4096];
  const int tid = threadIdx.x;
  const int l = tid & 63, w = tid >> 6;
  const int lr = l & 15, lg = l >> 4;
  const int wm = w >> 1, wn = w & 1;
  const int bm = blockIdx.x * 128, bn = blockIdx.y * 128;
  const int NT = K >> 6;

  // staging: thread covers slot j*256 + w*64 + l of each [A/B][ksub] region;
  // slot q <-> row q>>2, 8-col chunk q&3.
  const int srow = w * 16 + (l >> 2);
  const int scol = (l & 3) * 8;

  auto stage = [&](int t, int c) {
    const int k0 = t << 6;
    #pragma unroll
    for (int s = 0; s < 2; ++s)
      #pragma unroll
      for (int j = 0; j < 2; ++j) {
        gload_lds16(A  + (size_t)(bm + j * 64 + srow) * K + k0 + s * 32 + scol,
                    &lds[c][0][s][(j * 256 + w * 64) * 8]);
        gload_lds16(BT + (size_t)(bn + j * 64 + srow) * K + k0 + s * 32 + scol,
                    &lds[c][1][s][(j * 256 + w * 64) * 8]);
      }
  };

  f32x4 acc[4][4];
  #pragma unroll
  for (int m = 0; m < 4; ++m)
    #pragma unroll
    for (int n = 0; n < 4; ++n) {
      f32x4 z = {0.f, 0.f, 0.f, 0.f};
      acc[m][n] = z;
    }

  // prologue: tiles 0,1 in flight; wait tile 0 (own 8 oldest), sync.
  stage(0, 0);
  stage(1, 1);
  asm volatile("s_waitcnt vmcnt(8)" ::: "memory");
  __builtin_amdgcn_sched_barrier(0);
  __builtin_amdgcn_s_barrier();

  for (int t = 0; t < NT; ++t) {
    const int c = t & 1;
    bf16x8 af[4][2], bfr[4][2];
    #pragma unroll
    for (int m = 0; m < 4; ++m)
      #pragma unroll
      for (int ks = 0; ks < 2; ++ks)
        af[m][ks] = *(const bf16x8*)&lds[c][0][ks][((wm * 64 + m * 16 + lr) * 4 + lg) * 8];
    #pragma unroll
    for (int n = 0; n < 4; ++n)
      #pragma unroll
      for (int ks = 0; ks < 2; ++ks)
        bfr[n][ks] = *(const bf16x8*)&lds[c][1][ks][((wn * 64 + n * 16 + lr) * 4 + lg) * 8];
    // all reads of buf c complete before any wave overwrites it
    asm volatile("s_waitcnt lgkmcnt(0)" ::: "memory");
    __builtin_amdgcn_sched_barrier(0);
    __builtin_amdgcn_s_barrier();
    if (t + 2 < NT) stage(t + 2, c);
    __builtin_amdgcn_s_setprio(1);
    #pragma unroll
    for (int m = 0; m < 4; ++m)
      #pragma unroll
      for (int n = 0; n < 4; ++n) {
        acc[m][n] = __builtin_amdgcn_mfma_f32_16x16x32_bf16(af[m][0], bfr[n][0], acc[m][n], 0, 0, 0);
        acc[m][n] = __builtin_amdgcn_mfma_f32_16x16x32_bf16(af[m][1], bfr[n][1], acc[m][n], 0, 0, 0);
      }
    __builtin_amdgcn_s_setprio(0);
    // counted wait: tile t+1's 8 loads are the oldest outstanding
    if (t + 2 < NT) {
      asm volatile("s_waitcnt vmcnt(8)" ::: "memory");
    } else if (t + 1 < NT) {
      asm volatile("s_waitcnt vmcnt(0)" ::: "memory");
    }
    __builtin_amdgcn_sched_barrier(0);
    __builtin_amdgcn_s_barrier();
  }

  #pragma unroll
  for (int m = 0; m < 4; ++m)
    #pragma unroll
    for (int n = 0; n < 4; ++n)
      #pragma unroll
      for (int r = 0; r < 4; ++r) {
        int row = bm + wm * 64 + m * 16 + lg * 4 + r;
        int col = bn + wn * 64 + n * 16 + lr;
        if (BF16_OUT)
          ((short*)Cout)[(size_t)row * N + col] = f2b(acc[m][n][r]);
        else
          ((float*)Cout)[(size_t)row * N + col] = acc[m][n][r];
      }
}

// ---------------- RoPE + split qkv -> Q [b][h][s][64] (PRESCALED), K [b][kvh][s][64] ----------------
__global__ __launch_bounds__(256) void rope_split(const short* __restrict__ qkv,
                                                  const float* __restrict__ ctab,
                                                  const float* __restrict__ stab,
                                                  short* __restrict__ Qo,
                                                  short* __restrict__ Ko) {
  int w = threadIdx.x >> 6, l = threadIdx.x & 63;
  int job = blockIdx.x * 4 + w;
  int b = job / (SSEQ * 40);
  int rem = job % (SSEQ * 40);
  int s = rem / 40;
  int hh = rem % 40;
  size_t base = (size_t)(b * SSEQ + s) * PACKED;
  int off = (hh < 32) ? (hh * HD + l) : (DIME + (hh - 32) * HD + l);
  float x = b2f(qkv[base + off]);
  float other = __shfl_xor(x, 1);
  int i = l >> 1;
  float cs = ctab[s * 32 + i], sn = stab[s * 32 + i];
  float o = (l & 1) ? (x * cs + other * sn) : (x * cs - other * sn);
  if (hh < 32) {
    o *= 0.180336880f;  // 0.125 * log2(e)
    Qo[((size_t)(b * NH + hh) * SSEQ + s) * HD + l] = f2b(o);
  } else {
    Ko[((size_t)(b * NKV + (hh - 32)) * SSEQ + s) * HD + l] = f2b(o);
  }
}

// ---------------- V transpose: qkv v-slice [s][64] -> VT [b][kvh][64][S] ----------------
__global__ __launch_bounds__(256) void v_transpose(const short* __restrict__ qkv,
                                                   short* __restrict__ VT) {
  __shared__ __align__(16) short tile[64][72];
  int bkv = blockIdx.x >> 5;
  int st = blockIdx.x & 31;
  int s0 = st * 64;
  int t = threadIdx.x;
  int srow = t >> 2, dq = (t & 3) * 16;
  size_t rowbase = (size_t)((bkv >> 3) * SSEQ + s0 + srow) * PACKED
                   + (DIME + NKV * HD) + (bkv & 7) * HD + dq;
  bf16x8 v0 = *(const bf16x8*)&qkv[rowbase];
  bf16x8 v1 = *(const bf16x8*)&qkv[rowbase + 8];
  #pragma unroll
  for (int j = 0; j < 8; ++j) tile[dq + j][srow] = v0[j];
  #pragma unroll
  for (int j = 0; j < 8; ++j) tile[dq + 8 + j][srow] = v1[j];
  __syncthreads();
  int d = t >> 2, sq = (t & 3) * 16;
  size_t obase = ((size_t)bkv * HD + d) * SSEQ + s0 + sq;
  *(bf16x8*)&VT[obase]     = *(const bf16x8*)&tile[d][sq];
  *(bf16x8*)&VT[obase + 8] = *(const bf16x8*)&tile[d][sq + 8];
}

// ---------------- Flash attention: causal GQA, v7 ----------------
// v6 + early V issue: vf loads issued right after the QK^T MFMAs (kf dies
// there, so peak VGPR is ~neutral); V's ~300-cyc L2 latency hides under
// mask+defer-max+exp2+pack instead of sitting on the critical path.
__global__ __launch_bounds__(256) void attn_fwd(const short* __restrict__ Q,
                                                const short* __restrict__ K,
                                                const short* __restrict__ VT,
                                                short* __restrict__ Aout) {
  const int tid = threadIdx.x, l = tid & 63, w = tid >> 6;
  const int l31 = l & 31;
  const int hi = l >> 5;
  const int c = 63 - (blockIdx.x >> 4);    // chunk index, heavy first
  const int bh = (blockIdx.x & 15) * 4 + w;
  const int b = bh >> 5, hh = bh & 31, kvh = hh >> 2;
  const short* Qp = Q + (size_t)(b * NH + hh) * SSEQ * HD;
  const short* Kp = K + (size_t)(b * NKV + kvh) * SSEQ * HD;
  const short* Vp = VT + (size_t)(b * NKV + kvh) * HD * SSEQ;
  const int q0 = c * 32;
  const int qrow = q0 + l31;

  bf16x8 qf[4];
  #pragma unroll
  for (int ks = 0; ks < 4; ++ks)
    qf[ks] = *(const bf16x8*)&Qp[(size_t)qrow * HD + ks * 16 + hi * 8];

  f32x16 O0, O1;
  #pragma unroll
  for (int r = 0; r < 16; ++r) { O0[r] = 0.f; O1[r] = 0.f; }
  float mrun = -3.0e38f, lsum = 0.f;

  auto step = [&](int kv0, auto diag_tag) {
    constexpr bool DIAG = decltype(diag_tag)::value;
    bf16x8 kf0[4], kf1[4];
    #pragma unroll
    for (int ks = 0; ks < 4; ++ks) {
      kf0[ks] = *(const bf16x8*)&Kp[(size_t)(kv0 + l31) * HD + ks * 16 + hi * 8];
      kf1[ks] = *(const bf16x8*)&Kp[(size_t)(kv0 + 32 + l31) * HD + ks * 16 + hi * 8];
    }
    f32x16 sacc[2];
    #pragma unroll
    for (int r = 0; r < 16; ++r) { sacc[0][r] = 0.f; sacc[1][r] = 0.f; }
    #pragma unroll
    for (int ks = 0; ks < 4; ++ks) {
      sacc[0] = __builtin_amdgcn_mfma_f32_32x32x16_bf16(kf0[ks], qf[ks], sacc[0], 0, 0, 0);
      sacc[1] = __builtin_amdgcn_mfma_f32_32x32x16_bf16(kf1[ks], qf[ks], sacc[1], 0, 0, 0);
    }
    // early V issue: kf is dead now; V latency hides under softmax+pack
    bf16x8 vf0[4], vf1[4];
    #pragma unroll
    for (int ks = 0; ks < 4; ++ks) {
      vf0[ks] = *(const bf16x8*)&Vp[(size_t)l31 * SSEQ + kv0 + ks * 16 + hi * 8];
      vf1[ks] = *(const bf16x8*)&Vp[(size_t)(32 + l31) * SSEQ + kv0 + ks * 16 + hi * 8];
    }
    float pm = -3.0e38f;
    #pragma unroll
    for (int n = 0; n < 2; ++n)
      #pragma unroll
      for (int r = 0; r < 16; ++r) {
        if (DIAG) {
          int kvg = kv0 + n * 32 + ((r & 3) + 8 * (r >> 2)) + 4 * hi;
          if (kvg > qrow) sacc[n][r] = -3.0e38f;
        }
        pm = fmaxf(pm, sacc[n][r]);
      }
    pm = fmaxf(pm, __shfl_xor(pm, 32));
    if (!__all(pm <= mrun + 11.0f)) {
      float mn = fmaxf(mrun, pm);
      float corr = exp2f(mrun - mn);
      mrun = mn;
      lsum *= corr;
      #pragma unroll
      for (int r = 0; r < 16; ++r) {
        float cq = __shfl(corr, ((r & 3) + 8 * (r >> 2)) + 4 * hi);
        O0[r] *= cq;
        O1[r] *= cq;
      }
    }
    #pragma unroll
    for (int n = 0; n < 2; ++n)
      #pragma unroll
      for (int r = 0; r < 16; ++r) {
        float e = exp2f(sacc[n][r] - mrun);
        sacc[n][r] = e;
        lsum += e;
      }
    bf16x8 pa[4];
    #pragma unroll
    for (int n = 0; n < 2; ++n)
      #pragma unroll
      for (int s = 0; s < 2; ++s) {
        const int r0 = s * 8;
        unsigned A1 = cvt_pk(sacc[n][r0 + 0], sacc[n][r0 + 1]);
        unsigned B1 = cvt_pk(sacc[n][r0 + 4], sacc[n][r0 + 5]);
        unsigned A2 = cvt_pk(sacc[n][r0 + 2], sacc[n][r0 + 3]);
        unsigned B2 = cvt_pk(sacc[n][r0 + 6], sacc[n][r0 + 7]);
        unsigned shB1 = (unsigned)__shfl_xor((int)B1, 32);
        unsigned shA1 = (unsigned)__shfl_xor((int)A1, 32);
        unsigned shB2 = (unsigned)__shfl_xor((int)B2, 32);
        unsigned shA2 = (unsigned)__shfl_xor((int)A2, 32);
        u32x4 words;
        words[0] = hi ? shB1 : A1;
        words[1] = hi ? shB2 : A2;
        words[2] = hi ? B1 : shA1;
        words[3] = hi ? B2 : shA2;
        pa[n * 2 + s] = __builtin_bit_cast(bf16x8, words);
      }
    #pragma unroll
    for (int ks = 0; ks < 4; ++ks) {
      O0 = __builtin_amdgcn_mfma_f32_32x32x16_bf16(pa[ks], vf0[ks], O0, 0, 0, 0);
      O1 = __builtin_amdgcn_mfma_f32_32x32x16_bf16(pa[ks], vf1[ks], O1, 0, 0, 0);
    }
  };

  const int nkvt = (c >> 1) + 1;
  for (int kvt = 0; kvt < nkvt - 1; ++kvt) step(kvt * 64, FalseT{});
  step((nkvt - 1) * 64, TrueT{});

  lsum += __shfl_xor(lsum, 32);
  float inv = 1.0f / lsum;
  #pragma unroll
  for (int r = 0; r < 16; ++r) {
    int crow = (r & 3) + 8 * (r >> 2) + 4 * hi;
    float iq = __shfl(inv, crow);
    int qg = q0 + crow;
    size_t base = (size_t)(b * SSEQ + qg) * DIME + hh * HD;
    Aout[base + l31]      = f2b(O0[r] * iq);
    Aout[base + 32 + l31] = f2b(O1[r] * iq);
  }
}

extern "C" void kernel_launch(void* const* d_in, const int* in_sizes, int n_in,
                              void* d_out, int out_size, void* d_ws, size_t ws_size,
                              hipStream_t stream) {
  const float* x     = (const float*)d_in[0];
  const float* w_qkv = (const float*)d_in[1];
  const float* w_out = (const float*)d_in[2];
  float* out = (float*)d_out;

  char* ws = (char*)d_ws;
  size_t off = 0;
  auto alloc = [&](size_t bytes) -> void* {
    void* p = ws + off;
    off += (bytes + 255) & ~(size_t)255;
    return p;
  };
  short* xb    = (short*)alloc((size_t)MTOT * DIME * 2);
  short* wqkvT = (short*)alloc((size_t)PACKED * DIME * 2);
  short* woutT = (short*)alloc((size_t)DIME * DIME * 2);
  short* qkv   = (short*)alloc((size_t)MTOT * PACKED * 2);
  short* Qb    = (short*)alloc((size_t)BB * NH * SSEQ * HD * 2);
  short* Kb    = (short*)alloc((size_t)BB * NKV * SSEQ * HD * 2);
  short* VTb   = (short*)alloc((size_t)BB * NKV * HD * SSEQ * 2);
  float* ctab  = (float*)alloc((size_t)SSEQ * 32 * 4);
  float* stab  = (float*)alloc((size_t)SSEQ * 32 * 4);
  short* attnb = qkv;  // reuse: qkv dead after rope_split + v_transpose

  cast_bf16<<<2048, 256, 0, stream>>>(x, xb, MTOT * DIME / 4);
  transpose_cast<<<dim3(PACKED / 32, DIME / 32), dim3(32, 8), 0, stream>>>(w_qkv, wqkvT, DIME, PACKED);
  transpose_cast<<<dim3(DIME / 32, DIME / 32), dim3(32, 8), 0, stream>>>(w_out, woutT, DIME, DIME);
  rope_table<<<(SSEQ * 32) / 256, 256, 0, stream>>>(ctab, stab);

  gemm_bt<true><<<dim3(MTOT / 128, PACKED / 128), 256, 0, stream>>>(xb, wqkvT, qkv, MTOT, PACKED, DIME);

  rope_split<<<(BB * SSEQ * 40) / 4, 256, 0, stream>>>(qkv, ctab, stab, Qb, Kb);
  v_transpose<<<BB * NKV * (SSEQ / 64), 256, 0, stream>>>(qkv, VTb);

  attn_fwd<<<1024, 256, 0, stream>>>(Qb, Kb, VTb, attnb);

  gemm_bt<false><<<dim3(MTOT / 128, DIME / 128), 256, 0, stream>>>(attnb, woutT, out, MTOT, DIME, DIME);
}